// Round 1
// baseline (19357.254 us; speedup 1.0000x reference)
//
#include <hip/hip_runtime.h>

typedef __attribute__((ext_vector_type(8))) short bf8;
typedef __attribute__((ext_vector_type(8))) unsigned short us8;
typedef __attribute__((ext_vector_type(4))) unsigned short us4;
typedef __attribute__((ext_vector_type(4))) float f4;

#define NB 256
#define OUT_HX_OFF ((size_t)256 * 256 * 1024)
#define OUT_CX_OFF (OUT_HX_OFF + (size_t)256 * 1024)

static __device__ __forceinline__ unsigned short f2bf(float f) {
    unsigned u = __builtin_bit_cast(unsigned, f);
    return (unsigned short)((u + 0x7FFFu + ((u >> 16) & 1u)) >> 16);
}
static __device__ __forceinline__ float bf2f(unsigned short h) {
    return __builtin_bit_cast(float, (unsigned)h << 16);
}
static __device__ __forceinline__ float sigm(float x) {
    return 1.0f / (1.0f + __expf(-x));
}

// ---------------- one-time weight transpose f32[K][N] -> bf16[N][K] ----------------
__global__ __launch_bounds__(256) void k_transpose(const float* __restrict__ src,
                                                   unsigned short* __restrict__ dst,
                                                   int K, int N) {
    __shared__ float tile[32][33];
    const int tx = threadIdx.x & 31, ty = threadIdx.x >> 5;
    const int n0 = blockIdx.x * 32, k0 = blockIdx.y * 32;
#pragma unroll
    for (int i = 0; i < 4; ++i) {
        const int k = k0 + ty + i * 8;
        tile[ty + i * 8][tx] = src[(size_t)k * N + n0 + tx];
    }
    __syncthreads();
#pragma unroll
    for (int i = 0; i < 4; ++i) {
        const int n = n0 + ty + i * 8;
        dst[(size_t)n * K + k0 + tx] = f2bf(tile[tx][ty + i * 8]);
    }
}

// ---------------- stage 1: pre = [x_t ; h] @ Wg + bg ----------------
// grid (64 n-tiles, 4 b-tiles), block 256.  N=4096 (4 gates), K=2048.
__global__ __launch_bounds__(256) void k_pre(
    const float* __restrict__ x_t,
    const unsigned short* __restrict__ hxbf,
    const unsigned short* __restrict__ wgT,   // [4096][2048] bf16
    const float* __restrict__ bg,             // [4096]
    unsigned short* __restrict__ prebf,       // [3][B][1024] (gates 0,1,3)
    float* __restrict__ gupd)                 // [B][1024] = tanh(pre[2])
{
    __shared__ unsigned short Asm[2][64][72];
    __shared__ unsigned short Bsm[2][64][72];
    const int tid = threadIdx.x;
    const int n0 = blockIdx.x * 64;
    const int b0 = blockIdx.y * 64;
    const int lane = tid & 63, wave = tid >> 6;
    const int wr = (wave >> 1) * 32, wc = (wave & 1) * 32;
    const int fr = lane & 15, fq = lane >> 4;
    const int r = tid >> 2, q = (tid & 3) * 16;

    f4 acc[2][2];
#pragma unroll
    for (int i = 0; i < 2; ++i)
#pragma unroll
        for (int j = 0; j < 2; ++j) acc[i][j] = (f4)0.0f;

    f4 fv0, fv1, fv2, fv3;
    us8 hv0, hv1, bv0, bv1;

    for (int it = 0; it <= 32; ++it) {
        const bool isx = it < 16;
        if (it < 32) {
            const int k0 = it * 64;
            if (isx) {
                const float* s = x_t + (size_t)(b0 + r) * 1024 + k0 + q;
                fv0 = *(const f4*)(s);
                fv1 = *(const f4*)(s + 4);
                fv2 = *(const f4*)(s + 8);
                fv3 = *(const f4*)(s + 12);
            } else {
                const unsigned short* s = hxbf + (size_t)(b0 + r) * 1024 + (k0 - 1024) + q;
                hv0 = *(const us8*)(s);
                hv1 = *(const us8*)(s + 8);
            }
            const unsigned short* sb = wgT + (size_t)(n0 + r) * 2048 + k0 + q;
            bv0 = *(const us8*)(sb);
            bv1 = *(const us8*)(sb + 8);
        }
        if (it > 0) {
            const int buf = (it - 1) & 1;
#pragma unroll
            for (int ks = 0; ks < 2; ++ks) {
                const int kf = ks * 32 + fq * 8;
                bf8 a0 = *(const bf8*)&Asm[buf][wr + fr][kf];
                bf8 a1 = *(const bf8*)&Asm[buf][wr + 16 + fr][kf];
                bf8 b0 = *(const bf8*)&Bsm[buf][wc + fr][kf];
                bf8 b1 = *(const bf8*)&Bsm[buf][wc + 16 + fr][kf];
                acc[0][0] = __builtin_amdgcn_mfma_f32_16x16x32_bf16(a0, b0, acc[0][0], 0, 0, 0);
                acc[0][1] = __builtin_amdgcn_mfma_f32_16x16x32_bf16(a0, b1, acc[0][1], 0, 0, 0);
                acc[1][0] = __builtin_amdgcn_mfma_f32_16x16x32_bf16(a1, b0, acc[1][0], 0, 0, 0);
                acc[1][1] = __builtin_amdgcn_mfma_f32_16x16x32_bf16(a1, b1, acc[1][1], 0, 0, 0);
            }
        }
        __syncthreads();
        if (it < 32) {
            const int buf = it & 1;
            if (isx) {
                us8 c0, c1;
#pragma unroll
                for (int j = 0; j < 4; ++j) {
                    c0[j] = f2bf(fv0[j]); c0[4 + j] = f2bf(fv1[j]);
                    c1[j] = f2bf(fv2[j]); c1[4 + j] = f2bf(fv3[j]);
                }
                *(us8*)&Asm[buf][r][q] = c0;
                *(us8*)&Asm[buf][r][q + 8] = c1;
            } else {
                *(us8*)&Asm[buf][r][q] = hv0;
                *(us8*)&Asm[buf][r][q + 8] = hv1;
            }
            *(us8*)&Bsm[buf][r][q] = bv0;
            *(us8*)&Bsm[buf][r][q + 8] = bv1;
        }
        __syncthreads();
    }

#pragma unroll
    for (int mi = 0; mi < 2; ++mi)
#pragma unroll
        for (int ni = 0; ni < 2; ++ni) {
            const int col = n0 + wc + ni * 16 + fr;
            const int gg = col >> 10, d = col & 1023;
            const float bias = bg[col];
#pragma unroll
            for (int j = 0; j < 4; ++j) {
                const int row = b0 + wr + mi * 16 + fq * 4 + j;
                const float v = acc[mi][ni][j] + bias;
                if (gg == 2) {
                    gupd[(size_t)row * 1024 + d] = tanhf(v);
                } else {
                    const int gm = (gg == 3) ? 2 : gg;
                    prebf[((size_t)gm * NB + row) * 1024 + d] = f2bf(v);
                }
            }
        }
}

// ---------------- stage 2: qkv[g] = pre[g] @ Wqkv[g] + b ----------------
// grid (48 n-tiles, 4 b-tiles, 3 gates), block 256.  N=3072, K=1024 per gate.
__global__ __launch_bounds__(256) void k_qkv(
    const unsigned short* __restrict__ prebf,
    const unsigned short* __restrict__ wqkvT,  // [3][3072][1024] bf16
    const float* __restrict__ bq,
    const float* __restrict__ bk,
    const float* __restrict__ bv,
    unsigned short* __restrict__ qkvbf)        // [3][B][3072]
{
    __shared__ unsigned short Asm[2][64][72];
    __shared__ unsigned short Bsm[2][64][72];
    const int tid = threadIdx.x;
    const int g = blockIdx.z;
    const int n0 = blockIdx.x * 64;
    const int b0 = blockIdx.y * 64;
    const unsigned short* Aab = prebf + (size_t)g * NB * 1024;
    const unsigned short* Bb = wqkvT + (size_t)g * 3072 * 1024;
    const int lane = tid & 63, wave = tid >> 6;
    const int wr = (wave >> 1) * 32, wc = (wave & 1) * 32;
    const int fr = lane & 15, fq = lane >> 4;
    const int r = tid >> 2, q = (tid & 3) * 16;

    f4 acc[2][2];
#pragma unroll
    for (int i = 0; i < 2; ++i)
#pragma unroll
        for (int j = 0; j < 2; ++j) acc[i][j] = (f4)0.0f;

    us8 av0, av1, bv0, bv1;
    for (int it = 0; it <= 16; ++it) {
        if (it < 16) {
            const int k0 = it * 64;
            const unsigned short* sa = Aab + (size_t)(b0 + r) * 1024 + k0 + q;
            av0 = *(const us8*)(sa);
            av1 = *(const us8*)(sa + 8);
            const unsigned short* sb = Bb + (size_t)(n0 + r) * 1024 + k0 + q;
            bv0 = *(const us8*)(sb);
            bv1 = *(const us8*)(sb + 8);
        }
        if (it > 0) {
            const int buf = (it - 1) & 1;
#pragma unroll
            for (int ks = 0; ks < 2; ++ks) {
                const int kf = ks * 32 + fq * 8;
                bf8 a0 = *(const bf8*)&Asm[buf][wr + fr][kf];
                bf8 a1 = *(const bf8*)&Asm[buf][wr + 16 + fr][kf];
                bf8 b0 = *(const bf8*)&Bsm[buf][wc + fr][kf];
                bf8 b1 = *(const bf8*)&Bsm[buf][wc + 16 + fr][kf];
                acc[0][0] = __builtin_amdgcn_mfma_f32_16x16x32_bf16(a0, b0, acc[0][0], 0, 0, 0);
                acc[0][1] = __builtin_amdgcn_mfma_f32_16x16x32_bf16(a0, b1, acc[0][1], 0, 0, 0);
                acc[1][0] = __builtin_amdgcn_mfma_f32_16x16x32_bf16(a1, b0, acc[1][0], 0, 0, 0);
                acc[1][1] = __builtin_amdgcn_mfma_f32_16x16x32_bf16(a1, b1, acc[1][1], 0, 0, 0);
            }
        }
        __syncthreads();
        if (it < 16) {
            const int buf = it & 1;
            *(us8*)&Asm[buf][r][q] = av0;
            *(us8*)&Asm[buf][r][q + 8] = av1;
            *(us8*)&Bsm[buf][r][q] = bv0;
            *(us8*)&Bsm[buf][r][q + 8] = bv1;
        }
        __syncthreads();
    }

#pragma unroll
    for (int mi = 0; mi < 2; ++mi)
#pragma unroll
        for (int ni = 0; ni < 2; ++ni) {
            const int col = n0 + wc + ni * 16 + fr;
            const int which = col >> 10, d = col & 1023;
            const float* bp = which == 0 ? bq : (which == 1 ? bk : bv);
            const float bias = bp[g * 1024 + d];
#pragma unroll
            for (int j = 0; j < 4; ++j) {
                const int row = b0 + wr + mi * 16 + fq * 4 + j;
                qkvbf[((size_t)g * NB + row) * 3072 + col] = f2bf(acc[mi][ni][j] + bias);
            }
        }
}

// ---------------- stage 3: cross-head attention, one WG per batch ----------------
__global__ __launch_bounds__(256) void k_attn(
    const unsigned short* __restrict__ qkvbf,
    unsigned short* __restrict__ aobf)   // [3][B][1024]
{
    __shared__ unsigned short qs[16][72], ksm[16][72], vsm[16][72];
    __shared__ float aw[16][17];
    const int b = blockIdx.x;
    const int tid = threadIdx.x;
    for (int g = 0; g < 3; ++g) {
        const unsigned short* src = qkvbf + ((size_t)g * NB + b) * 3072;
#pragma unroll
        for (int j = 0; j < 3; ++j) {
            const int n = (tid + j * 256) * 4;
            us4 dv = *(const us4*)(src + n);
            const int part = n >> 10, h = (n >> 6) & 15, c = n & 63;
            unsigned short* dst = part == 0 ? &qs[h][c] : (part == 1 ? &ksm[h][c] : &vsm[h][c]);
            *(us4*)dst = dv;
        }
        __syncthreads();
        const int h = tid >> 4, kp = tid & 15;
        float s = 0.f;
#pragma unroll
        for (int dblk = 0; dblk < 8; ++dblk) {
            us8 qv = *(const us8*)&qs[h][dblk * 8];
            us8 kv = *(const us8*)&ksm[kp][dblk * 8];
#pragma unroll
            for (int e = 0; e < 8; ++e) s += bf2f(qv[e]) * bf2f(kv[e]);
        }
        s *= 0.125f;  // 1/sqrt(64)
        float m = s;
#pragma unroll
        for (int off = 8; off; off >>= 1) m = fmaxf(m, __shfl_xor(m, off, 16));
        const float p = __expf(s - m);
        float sum = p;
#pragma unroll
        for (int off = 8; off; off >>= 1) sum += __shfl_xor(sum, off, 16);
        aw[h][kp] = p / sum;
        __syncthreads();
        const int dg = tid & 15;
        float a0 = 0.f, a1 = 0.f, a2 = 0.f, a3 = 0.f;
#pragma unroll
        for (int kk = 0; kk < 16; ++kk) {
            const float w = aw[h][kk];
            us4 vv = *(const us4*)&vsm[kk][dg * 4];
            a0 += w * bf2f(vv[0]);
            a1 += w * bf2f(vv[1]);
            a2 += w * bf2f(vv[2]);
            a3 += w * bf2f(vv[3]);
        }
        us4 ov;
        ov[0] = f2bf(a0); ov[1] = f2bf(a1); ov[2] = f2bf(a2); ov[3] = f2bf(a3);
        *(us4*)(aobf + ((size_t)g * NB + b) * 1024 + h * 64 + dg * 4) = ov;
        __syncthreads();
    }
}

// ---------------- stage 4: gates = sigmoid(ao @ Wo + bo); cell update ----------------
// grid (32 d-tiles, 8 b-tiles), block 256, tile 32x32, 3 gate-GEMMs fused.
__global__ __launch_bounds__(256) void k_gate(
    const unsigned short* __restrict__ aobf,
    const unsigned short* __restrict__ woT,  // [3][1024][1024] bf16 [n][k]
    const float* __restrict__ bo,            // [3][1024]
    const float* __restrict__ gupd,
    unsigned short* __restrict__ hxbf,
    float* __restrict__ out,
    int t)
{
    __shared__ unsigned short Asm[2][32][72];
    __shared__ unsigned short Bsm[2][32][72];
    const int tid = threadIdx.x;
    const int d0 = blockIdx.x * 32, b0 = blockIdx.y * 32;
    const int lane = tid & 63, wave = tid >> 6;
    const int wr = (wave >> 1) * 16, wc = (wave & 1) * 16;
    const int fr = lane & 15, fq = lane >> 4;
    const int r = tid >> 3, q = (tid & 7) * 8;

    f4 acc0 = (f4)0.0f, acc1 = (f4)0.0f, acc2 = (f4)0.0f;
    us8 av, bvv;
    for (int gi = 0; gi <= 48; ++gi) {
        if (gi < 48) {
            const int g = gi >> 4, k0 = (gi & 15) * 64;
            av = *(const us8*)(aobf + ((size_t)g * NB + b0 + r) * 1024 + k0 + q);
            bvv = *(const us8*)(woT + ((size_t)g * 1024 + d0 + r) * 1024 + k0 + q);
        }
        if (gi > 0) {
            const int buf = (gi - 1) & 1, gp = (gi - 1) >> 4;
            bf8 a0 = *(const bf8*)&Asm[buf][wr + fr][fq * 8];
            bf8 b0 = *(const bf8*)&Bsm[buf][wc + fr][fq * 8];
            bf8 a1 = *(const bf8*)&Asm[buf][wr + fr][32 + fq * 8];
            bf8 b1 = *(const bf8*)&Bsm[buf][wc + fr][32 + fq * 8];
            if (gp == 0) {
                acc0 = __builtin_amdgcn_mfma_f32_16x16x32_bf16(a0, b0, acc0, 0, 0, 0);
                acc0 = __builtin_amdgcn_mfma_f32_16x16x32_bf16(a1, b1, acc0, 0, 0, 0);
            } else if (gp == 1) {
                acc1 = __builtin_amdgcn_mfma_f32_16x16x32_bf16(a0, b0, acc1, 0, 0, 0);
                acc1 = __builtin_amdgcn_mfma_f32_16x16x32_bf16(a1, b1, acc1, 0, 0, 0);
            } else {
                acc2 = __builtin_amdgcn_mfma_f32_16x16x32_bf16(a0, b0, acc2, 0, 0, 0);
                acc2 = __builtin_amdgcn_mfma_f32_16x16x32_bf16(a1, b1, acc2, 0, 0, 0);
            }
        }
        __syncthreads();
        if (gi < 48) {
            const int buf = gi & 1;
            *(us8*)&Asm[buf][r][q] = av;
            *(us8*)&Bsm[buf][r][q] = bvv;
        }
        __syncthreads();
    }

    const int col = d0 + wc + fr;
    const float bof = bo[col], boi = bo[1024 + col], boo = bo[2048 + col];
    float* cxp = out + OUT_CX_OFF;
    float* hxp = out + OUT_HX_OFF;
    float* outs = out + (size_t)t * NB * 1024;
#pragma unroll
    for (int j = 0; j < 4; ++j) {
        const int row = b0 + wr + fq * 4 + j;
        const size_t idx = (size_t)row * 1024 + col;
        const float fg = sigm(acc0[j] + bof);
        const float ig = sigm(acc1[j] + boi);
        const float og = sigm(acc2[j] + boo);
        const float c = fg * cxp[idx] + ig * gupd[idx];
        const float h = og * tanhf(c);
        cxp[idx] = c;
        hxp[idx] = h;
        outs[idx] = h;
        hxbf[idx] = f2bf(h);
    }
}

extern "C" void kernel_launch(void* const* d_in, const int* in_sizes, int n_in,
                              void* d_out, int out_size, void* d_ws, size_t ws_size,
                              hipStream_t stream) {
    const float* inputs = (const float*)d_in[0];
    const float* Wg = (const float*)d_in[1];
    const float* bg = (const float*)d_in[2];
    const float* Wq = (const float*)d_in[3];
    const float* bq = (const float*)d_in[4];
    const float* Wk = (const float*)d_in[5];
    const float* bk = (const float*)d_in[6];
    const float* Wv = (const float*)d_in[7];
    const float* bv = (const float*)d_in[8];
    const float* Wo = (const float*)d_in[9];
    const float* bo = (const float*)d_in[10];
    float* out = (float*)d_out;
    (void)in_sizes; (void)n_in; (void)out_size;

    char* ws = (char*)d_ws;
    size_t off = 0;
    auto alloc = [&](size_t bytes) -> void* {
        void* p = ws + off;
        off += (bytes + 255) & ~(size_t)255;
        return p;
    };
    unsigned short* wgT   = (unsigned short*)alloc((size_t)4096 * 2048 * 2);
    unsigned short* wqkvT = (unsigned short*)alloc((size_t)3 * 3072 * 1024 * 2);
    unsigned short* woT   = (unsigned short*)alloc((size_t)3 * 1024 * 1024 * 2);
    unsigned short* hxbf  = (unsigned short*)alloc((size_t)256 * 1024 * 2);
    unsigned short* prebf = (unsigned short*)alloc((size_t)3 * 256 * 1024 * 2);
    float*          gupd  = (float*)alloc((size_t)256 * 1024 * 4);
    unsigned short* qkvbf = (unsigned short*)alloc((size_t)3 * 256 * 3072 * 2);
    unsigned short* aobf  = (unsigned short*)alloc((size_t)3 * 256 * 1024 * 2);
    if (ws_size < off) return;  // insufficient scratch: fail cleanly

    // zero the recurrent state (cx slot in d_out, bf16 h in ws)
    hipMemsetAsync(hxbf, 0, (size_t)256 * 1024 * 2, stream);
    hipMemsetAsync(out + OUT_CX_OFF, 0, (size_t)256 * 1024 * 4, stream);

    // one-time weight convert+transpose
    for (int g = 0; g < 4; ++g)
        k_transpose<<<dim3(32, 64), 256, 0, stream>>>(
            Wg + (size_t)g * 2048 * 1024, wgT + (size_t)g * 1024 * 2048, 2048, 1024);
    const float* wsrc[3] = {Wq, Wk, Wv};
    for (int g = 0; g < 3; ++g)
        for (int wi = 0; wi < 3; ++wi)
            k_transpose<<<dim3(32, 32), 256, 0, stream>>>(
                wsrc[wi] + (size_t)g * 1024 * 1024,
                wqkvT + (size_t)g * 3072 * 1024 + (size_t)wi * 1024 * 1024, 1024, 1024);
    for (int g = 0; g < 3; ++g)
        k_transpose<<<dim3(32, 32), 256, 0, stream>>>(
            Wo + (size_t)g * 1024 * 1024, woT + (size_t)g * 1024 * 1024, 1024, 1024);

    for (int t = 0; t < 256; ++t) {
        k_pre<<<dim3(64, 4), 256, 0, stream>>>(
            inputs + (size_t)t * 256 * 1024, hxbf, wgT, bg, prebf, gupd);
        k_qkv<<<dim3(48, 4, 3), 256, 0, stream>>>(prebf, wqkvT, bq, bk, bv, qkvbf);
        k_attn<<<dim3(256), 256, 0, stream>>>(qkvbf, aobf);
        k_gate<<<dim3(32, 8), 256, 0, stream>>>(aobf, woT, bo, gupd, hxbf, out, t);
    }
}

// Round 2
// 16208.047 us; speedup vs baseline: 1.1943x; 1.1943x over previous
//
#include <hip/hip_runtime.h>

typedef __attribute__((ext_vector_type(8))) short bf8;
typedef __attribute__((ext_vector_type(8))) unsigned short us8;
typedef __attribute__((ext_vector_type(4))) unsigned short us4;
typedef __attribute__((ext_vector_type(4))) float f4;

#define NB 256
#define OUT_HX_OFF ((size_t)256 * 256 * 1024)
#define OUT_CX_OFF (OUT_HX_OFF + (size_t)256 * 1024)

static __device__ __forceinline__ unsigned short f2bf(float f) {
    unsigned u = __builtin_bit_cast(unsigned, f);
    return (unsigned short)((u + 0x7FFFu + ((u >> 16) & 1u)) >> 16);
}
static __device__ __forceinline__ float bf2f(unsigned short h) {
    return __builtin_bit_cast(float, (unsigned)h << 16);
}
static __device__ __forceinline__ float sigm(float x) {
    return 1.0f / (1.0f + __expf(-x));
}

#define MFMA16(a, b, c) __builtin_amdgcn_mfma_f32_16x16x32_bf16(a, b, c, 0, 0, 0)

#define GLDS16(g, l)                                                        \
    __builtin_amdgcn_global_load_lds(                                       \
        (const __attribute__((address_space(1))) void*)(g),                 \
        (__attribute__((address_space(3))) void*)(l), 16, 0, 0)

#define WAITV(n) asm volatile("s_waitcnt vmcnt(" #n ")" ::: "memory")
#define WAITL0 asm volatile("s_waitcnt lgkmcnt(0)" ::: "memory")
#define BARRIER                                                             \
    do {                                                                    \
        __builtin_amdgcn_s_barrier();                                       \
        __builtin_amdgcn_sched_barrier(0);                                  \
    } while (0)

// Stage R rows x 64 bf16 cols into LDS (linear row-major, 128B rows) via
// global_load_lds.  Source chunk is pre-swizzled (chunk ^= row&7) so the
// read side can XOR the same way -> conflict-free ds_read_b128.
template <int R>
static __device__ __forceinline__ void stage64(const unsigned short* g, int gstride,
                                               unsigned short* lds, int wave, int lane) {
#pragma unroll
    for (int j = 0; j < R / 32; ++j) {
        const int seg = wave * (R / 32) + j;
        const int row = seg * 8 + (lane >> 3);
        const int chunk = (lane & 7) ^ (row & 7);
        GLDS16(g + (size_t)row * gstride + chunk * 8, lds + seg * 512);
    }
}

static __device__ __forceinline__ bf8 fragld(const unsigned short* lds, int row, int ck) {
    return *(const bf8*)&lds[row * 64 + (((ck) ^ (row & 7)) << 3)];
}

// ---------------- one-time: f32 -> bf16 convert (grid-stride over float4) ----------------
__global__ __launch_bounds__(256) void k_x2bf(const float* __restrict__ src,
                                              unsigned short* __restrict__ dst, int n4) {
    const int stride = gridDim.x * 256;
    for (int i = blockIdx.x * 256 + threadIdx.x; i < n4; i += stride) {
        f4 v = ((const f4*)src)[i];
        us4 o;
        o[0] = f2bf(v[0]); o[1] = f2bf(v[1]); o[2] = f2bf(v[2]); o[3] = f2bf(v[3]);
        ((us4*)dst)[i] = o;
    }
}

// ---------------- one-time: weight transpose f32[K][N] -> bf16[N][K] ----------------
__global__ __launch_bounds__(256) void k_transpose(const float* __restrict__ src,
                                                   unsigned short* __restrict__ dst,
                                                   int K, int N) {
    __shared__ float tile[32][33];
    const int tx = threadIdx.x & 31, ty = threadIdx.x >> 5;
    const int n0 = blockIdx.x * 32, k0 = blockIdx.y * 32;
#pragma unroll
    for (int i = 0; i < 4; ++i) tile[ty + i * 8][tx] = src[(size_t)(k0 + ty + i * 8) * N + n0 + tx];
    __syncthreads();
#pragma unroll
    for (int i = 0; i < 4; ++i)
        dst[(size_t)(n0 + ty + i * 8) * K + k0 + tx] = f2bf(tile[tx][ty + i * 8]);
}

// ---------------- one-time: xpre = X @ Wg_x + bg  (M=65536, N=4096, K=1024) ----------------
__global__ __launch_bounds__(256) void k_xpre(const unsigned short* __restrict__ xbf,
                                              const unsigned short* __restrict__ wgT,
                                              const float* __restrict__ bg,
                                              unsigned short* __restrict__ xpre) {
    __shared__ unsigned short sA[2][128 * 64];
    __shared__ unsigned short sB[2][128 * 64];
    const int tid = threadIdx.x, lane = tid & 63, wave = tid >> 6;
    const int n0 = blockIdx.x * 128;
    const size_t m0 = (size_t)blockIdx.y * 128;
    const int wy = (wave >> 1) * 64, wx = (wave & 1) * 64;
    const int fr = lane & 15, fq = lane >> 4;
    f4 acc[4][4] = {};

    stage64<128>(xbf + m0 * 1024, 1024, sA[0], wave, lane);
    stage64<128>(wgT + (size_t)n0 * 2048, 2048, sB[0], wave, lane);
    WAITV(0); BARRIER;
#pragma unroll
    for (int i = 0; i < 16; ++i) {
        if (i + 1 < 16) {
            stage64<128>(xbf + m0 * 1024 + (i + 1) * 64, 1024, sA[(i + 1) & 1], wave, lane);
            stage64<128>(wgT + (size_t)n0 * 2048 + (i + 1) * 64, 2048, sB[(i + 1) & 1], wave, lane);
        }
        const unsigned short* A = sA[i & 1];
        const unsigned short* Bm = sB[i & 1];
#pragma unroll
        for (int ks = 0; ks < 2; ++ks) {
            bf8 af[4], bfv[4];
#pragma unroll
            for (int mi = 0; mi < 4; ++mi) af[mi] = fragld(A, wy + mi * 16 + fr, ks * 4 + fq);
#pragma unroll
            for (int ni = 0; ni < 4; ++ni) bfv[ni] = fragld(Bm, wx + ni * 16 + fr, ks * 4 + fq);
#pragma unroll
            for (int mi = 0; mi < 4; ++mi)
#pragma unroll
                for (int ni = 0; ni < 4; ++ni)
                    acc[mi][ni] = MFMA16(af[mi], bfv[ni], acc[mi][ni]);
        }
        if (i + 1 < 16) { WAITL0; WAITV(0); BARRIER; }
    }
#pragma unroll
    for (int mi = 0; mi < 4; ++mi)
#pragma unroll
        for (int ni = 0; ni < 4; ++ni) {
            const int col = n0 + wx + ni * 16 + fr;
            const float b = bg[col];
#pragma unroll
            for (int j = 0; j < 4; ++j) {
                const size_t row = m0 + wy + mi * 16 + fq * 4 + j;
                xpre[row * 4096 + col] = f2bf(acc[mi][ni][j] + b);
            }
        }
}

// ---------------- per step: pre = xpre_t + h @ Wg_h (XP=1) or [x;h] @ Wg + bg (XP=0) ----------------
template <int XP>
__global__ __launch_bounds__(256) void k_hpre(const unsigned short* __restrict__ hxbf,
                                              const unsigned short* __restrict__ xt,
                                              const unsigned short* __restrict__ wgT,
                                              const float* __restrict__ bg,
                                              unsigned short* __restrict__ prebf,
                                              float* __restrict__ gupd) {
    __shared__ unsigned short sA[3][64 * 64];
    __shared__ unsigned short sB[3][64 * 64];
    const int tid = threadIdx.x, lane = tid & 63, wave = tid >> 6;
    const int n0 = blockIdx.x * 64, b0 = blockIdx.y * 64;
    const int wr = (wave >> 1) * 32, wc = (wave & 1) * 32;
    const int fr = lane & 15, fq = lane >> 4;
    constexpr int NT = XP ? 16 : 32;
    f4 acc[2][2] = {};

    auto asrc = [&](int i) -> const unsigned short* {
        if (XP) return hxbf + (size_t)b0 * 1024 + i * 64;
        return i < 16 ? xt + (size_t)b0 * 1024 + i * 64
                      : hxbf + (size_t)b0 * 1024 + (i - 16) * 64;
    };
    auto bsrc = [&](int i) -> const unsigned short* {
        return wgT + (size_t)n0 * 2048 + (XP ? 1024 : 0) + i * 64;
    };

    stage64<64>(asrc(0), 1024, sA[0], wave, lane);
    stage64<64>(bsrc(0), 2048, sB[0], wave, lane);
    stage64<64>(asrc(1), 1024, sA[1], wave, lane);
    stage64<64>(bsrc(1), 2048, sB[1], wave, lane);
    WAITV(4); BARRIER;
#pragma unroll
    for (int i = 0; i < NT; ++i) {
        if (i + 2 < NT) {
            stage64<64>(asrc(i + 2), 1024, sA[(i + 2) % 3], wave, lane);
            stage64<64>(bsrc(i + 2), 2048, sB[(i + 2) % 3], wave, lane);
        }
        const unsigned short* A = sA[i % 3];
        const unsigned short* Bm = sB[i % 3];
#pragma unroll
        for (int ks = 0; ks < 2; ++ks) {
            bf8 a0 = fragld(A, wr + fr, ks * 4 + fq);
            bf8 a1 = fragld(A, wr + 16 + fr, ks * 4 + fq);
            bf8 b0v = fragld(Bm, wc + fr, ks * 4 + fq);
            bf8 b1v = fragld(Bm, wc + 16 + fr, ks * 4 + fq);
            acc[0][0] = MFMA16(a0, b0v, acc[0][0]);
            acc[0][1] = MFMA16(a0, b1v, acc[0][1]);
            acc[1][0] = MFMA16(a1, b0v, acc[1][0]);
            acc[1][1] = MFMA16(a1, b1v, acc[1][1]);
        }
        if (i < NT - 1) {
            WAITL0;
            if (i + 2 < NT) { WAITV(4); } else { WAITV(0); }
            BARRIER;
        }
    }
#pragma unroll
    for (int mi = 0; mi < 2; ++mi)
#pragma unroll
        for (int ni = 0; ni < 2; ++ni) {
            const int col = n0 + wc + ni * 16 + fr;
            const int gg = col >> 10, d = col & 1023;
#pragma unroll
            for (int j = 0; j < 4; ++j) {
                const int row = b0 + wr + mi * 16 + fq * 4 + j;
                float v = acc[mi][ni][j];
                if (XP) v += bf2f(xt[(size_t)row * 4096 + col]);
                else v += bg[col];
                if (gg == 2) {
                    gupd[(size_t)row * 1024 + d] = tanhf(v);
                } else {
                    const int gm = (gg == 3) ? 2 : gg;
                    prebf[((size_t)gm * NB + row) * 1024 + d] = f2bf(v);
                }
            }
        }
}

// ---------------- per step: qkv[g] = pre[g] @ Wqkv[g] + b ----------------
__global__ __launch_bounds__(256) void k_qkv(const unsigned short* __restrict__ prebf,
                                             const unsigned short* __restrict__ wqkvT,
                                             const float* __restrict__ bq,
                                             const float* __restrict__ bk,
                                             const float* __restrict__ bv,
                                             unsigned short* __restrict__ qkvbf) {
    __shared__ unsigned short sA[3][64 * 64];
    __shared__ unsigned short sB[3][64 * 64];
    const int tid = threadIdx.x, lane = tid & 63, wave = tid >> 6;
    const int g = blockIdx.z;
    const int n0 = blockIdx.x * 64, b0 = blockIdx.y * 64;
    const unsigned short* Aab = prebf + (size_t)g * NB * 1024 + (size_t)b0 * 1024;
    const unsigned short* Bb = wqkvT + (size_t)g * 3072 * 1024 + (size_t)n0 * 1024;
    const int wr = (wave >> 1) * 32, wc = (wave & 1) * 32;
    const int fr = lane & 15, fq = lane >> 4;
    f4 acc[2][2] = {};

    stage64<64>(Aab, 1024, sA[0], wave, lane);
    stage64<64>(Bb, 1024, sB[0], wave, lane);
    stage64<64>(Aab + 64, 1024, sA[1], wave, lane);
    stage64<64>(Bb + 64, 1024, sB[1], wave, lane);
    WAITV(4); BARRIER;
#pragma unroll
    for (int i = 0; i < 16; ++i) {
        if (i + 2 < 16) {
            stage64<64>(Aab + (i + 2) * 64, 1024, sA[(i + 2) % 3], wave, lane);
            stage64<64>(Bb + (i + 2) * 64, 1024, sB[(i + 2) % 3], wave, lane);
        }
        const unsigned short* A = sA[i % 3];
        const unsigned short* Bm = sB[i % 3];
#pragma unroll
        for (int ks = 0; ks < 2; ++ks) {
            bf8 a0 = fragld(A, wr + fr, ks * 4 + fq);
            bf8 a1 = fragld(A, wr + 16 + fr, ks * 4 + fq);
            bf8 b0v = fragld(Bm, wc + fr, ks * 4 + fq);
            bf8 b1v = fragld(Bm, wc + 16 + fr, ks * 4 + fq);
            acc[0][0] = MFMA16(a0, b0v, acc[0][0]);
            acc[0][1] = MFMA16(a0, b1v, acc[0][1]);
            acc[1][0] = MFMA16(a1, b0v, acc[1][0]);
            acc[1][1] = MFMA16(a1, b1v, acc[1][1]);
        }
        if (i < 15) {
            WAITL0;
            if (i + 2 < 16) { WAITV(4); } else { WAITV(0); }
            BARRIER;
        }
    }
#pragma unroll
    for (int mi = 0; mi < 2; ++mi)
#pragma unroll
        for (int ni = 0; ni < 2; ++ni) {
            const int col = n0 + wc + ni * 16 + fr;
            const int which = col >> 10, d = col & 1023;
            const float* bp = which == 0 ? bq : (which == 1 ? bk : bv);
            const float bias = bp[g * 1024 + d];
#pragma unroll
            for (int j = 0; j < 4; ++j) {
                const int row = b0 + wr + mi * 16 + fq * 4 + j;
                qkvbf[((size_t)g * NB + row) * 3072 + col] = f2bf(acc[mi][ni][j] + bias);
            }
        }
}

// ---------------- per step: cross-head attention, one WG per batch ----------------
__global__ __launch_bounds__(256) void k_attn(const unsigned short* __restrict__ qkvbf,
                                              unsigned short* __restrict__ aobf) {
    __shared__ unsigned short qs[3][16][72], ksm[3][16][72], vsm[3][16][72];
    __shared__ float aw[3][16][17];
    const int b = blockIdx.x, tid = threadIdx.x;
#pragma unroll
    for (int j = 0; j < 9; ++j) {
        const int lin = j * 256 + tid;           // 0..2303 us4 chunks
        const int g = lin / 768, n = (lin % 768) * 4;
        us4 dv = *(const us4*)(qkvbf + ((size_t)g * NB + b) * 3072 + n);
        const int part = n >> 10, h = (n >> 6) & 15, c = n & 63;
        unsigned short* dst = part == 0 ? &qs[g][h][c] : (part == 1 ? &ksm[g][h][c] : &vsm[g][h][c]);
        *(us4*)dst = dv;
    }
    __syncthreads();
    const int h = tid >> 4, kp = tid & 15;
#pragma unroll
    for (int g = 0; g < 3; ++g) {
        float s = 0.f;
#pragma unroll
        for (int dblk = 0; dblk < 8; ++dblk) {
            us8 qv = *(const us8*)&qs[g][h][dblk * 8];
            us8 kv = *(const us8*)&ksm[g][kp][dblk * 8];
#pragma unroll
            for (int e = 0; e < 8; ++e) s += bf2f(qv[e]) * bf2f(kv[e]);
        }
        s *= 0.125f;
        float m = s;
#pragma unroll
        for (int off = 8; off; off >>= 1) m = fmaxf(m, __shfl_xor(m, off, 16));
        const float p = __expf(s - m);
        float sum = p;
#pragma unroll
        for (int off = 8; off; off >>= 1) sum += __shfl_xor(sum, off, 16);
        aw[g][h][kp] = p / sum;
    }
    __syncthreads();
#pragma unroll
    for (int g = 0; g < 3; ++g) {
        float a0 = 0.f, a1 = 0.f, a2 = 0.f, a3 = 0.f;
#pragma unroll
        for (int kk = 0; kk < 16; ++kk) {
            const float w = aw[g][h][kk];
            us4 vv = *(const us4*)&vsm[g][kk][kp * 4];
            a0 += w * bf2f(vv[0]); a1 += w * bf2f(vv[1]);
            a2 += w * bf2f(vv[2]); a3 += w * bf2f(vv[3]);
        }
        us4 ov;
        ov[0] = f2bf(a0); ov[1] = f2bf(a1); ov[2] = f2bf(a2); ov[3] = f2bf(a3);
        *(us4*)(aobf + ((size_t)g * NB + b) * 1024 + h * 64 + kp * 4) = ov;
    }
}

// ---------------- per step: gates = sigmoid(ao @ Wo + bo); cell update ----------------
__global__ __launch_bounds__(256) void k_gate(const unsigned short* __restrict__ aobf,
                                              const unsigned short* __restrict__ woT,
                                              const float* __restrict__ bo,
                                              const float* __restrict__ gupd,
                                              unsigned short* __restrict__ hxbf,
                                              float* __restrict__ out, int t) {
    __shared__ unsigned short sA[3][32 * 64];
    __shared__ unsigned short sB[3][32 * 64];
    const int tid = threadIdx.x, lane = tid & 63, wave = tid >> 6;
    const int d0 = blockIdx.x * 32, b0 = blockIdx.y * 32;
    const int wr = (wave >> 1) * 16, wc = (wave & 1) * 16;
    const int fr = lane & 15, fq = lane >> 4;
    f4 acc[3] = {};

    auto asrc = [&](int i) -> const unsigned short* {
        return aobf + ((size_t)(i >> 4) * NB + b0) * 1024 + (i & 15) * 64;
    };
    auto bsrc = [&](int i) -> const unsigned short* {
        return woT + ((size_t)(i >> 4) * 1024 + d0) * 1024 + (i & 15) * 64;
    };

    stage64<32>(asrc(0), 1024, sA[0], wave, lane);
    stage64<32>(bsrc(0), 1024, sB[0], wave, lane);
    stage64<32>(asrc(1), 1024, sA[1], wave, lane);
    stage64<32>(bsrc(1), 1024, sB[1], wave, lane);
    WAITV(2); BARRIER;
#pragma unroll
    for (int i = 0; i < 48; ++i) {
        if (i + 2 < 48) {
            stage64<32>(asrc(i + 2), 1024, sA[(i + 2) % 3], wave, lane);
            stage64<32>(bsrc(i + 2), 1024, sB[(i + 2) % 3], wave, lane);
        }
        const unsigned short* A = sA[i % 3];
        const unsigned short* Bm = sB[i % 3];
#pragma unroll
        for (int ks = 0; ks < 2; ++ks) {
            bf8 a0 = fragld(A, wr + fr, ks * 4 + fq);
            bf8 b0v = fragld(Bm, wc + fr, ks * 4 + fq);
            acc[i >> 4] = MFMA16(a0, b0v, acc[i >> 4]);
        }
        if (i < 47) {
            WAITL0;
            if (i + 2 < 48) { WAITV(2); } else { WAITV(0); }
            BARRIER;
        }
    }

    const int col = d0 + wc + fr;
    const float bof = bo[col], boi = bo[1024 + col], boo = bo[2048 + col];
    float* cxp = out + OUT_CX_OFF;
    float* hxp = out + OUT_HX_OFF;
    float* outs = out + (size_t)t * NB * 1024;
#pragma unroll
    for (int j = 0; j < 4; ++j) {
        const int row = b0 + wr + fq * 4 + j;
        const size_t idx = (size_t)row * 1024 + col;
        const float fg = sigm(acc[0][j] + bof);
        const float ig = sigm(acc[1][j] + boi);
        const float og = sigm(acc[2][j] + boo);
        const float c = fg * cxp[idx] + ig * gupd[idx];
        const float h = og * tanhf(c);
        cxp[idx] = c;
        hxp[idx] = h;
        outs[idx] = h;
        hxbf[idx] = f2bf(h);
    }
}

extern "C" void kernel_launch(void* const* d_in, const int* in_sizes, int n_in,
                              void* d_out, int out_size, void* d_ws, size_t ws_size,
                              hipStream_t stream) {
    const float* inputs = (const float*)d_in[0];
    const float* Wg = (const float*)d_in[1];
    const float* bg = (const float*)d_in[2];
    const float* Wq = (const float*)d_in[3];
    const float* bq = (const float*)d_in[4];
    const float* Wk = (const float*)d_in[5];
    const float* bk = (const float*)d_in[6];
    const float* Wv = (const float*)d_in[7];
    const float* bv = (const float*)d_in[8];
    const float* Wo = (const float*)d_in[9];
    const float* bo = (const float*)d_in[10];
    float* out = (float*)d_out;
    (void)in_sizes; (void)n_in; (void)out_size;

    char* ws = (char*)d_ws;
    size_t off = 0;
    auto alloc = [&](size_t bytes) -> void* {
        void* p = ws + off;
        off += (bytes + 255) & ~(size_t)255;
        return p;
    };
    unsigned short* wgT   = (unsigned short*)alloc((size_t)4096 * 2048 * 2);
    unsigned short* wqkvT = (unsigned short*)alloc((size_t)3 * 3072 * 1024 * 2);
    unsigned short* woT   = (unsigned short*)alloc((size_t)3 * 1024 * 1024 * 2);
    unsigned short* hxbf  = (unsigned short*)alloc((size_t)256 * 1024 * 2);
    unsigned short* prebf = (unsigned short*)alloc((size_t)3 * 256 * 1024 * 2);
    float*          gupd  = (float*)alloc((size_t)256 * 1024 * 4);
    unsigned short* qkvbf = (unsigned short*)alloc((size_t)3 * 256 * 3072 * 2);
    unsigned short* aobf  = (unsigned short*)alloc((size_t)3 * 256 * 1024 * 2);
    const size_t off_base = off;
    unsigned short* xbf   = (unsigned short*)alloc((size_t)65536 * 1024 * 2);
    const size_t off_t2 = off;
    unsigned short* xpre  = (unsigned short*)alloc((size_t)65536 * 4096 * 2);
    const size_t off_t1 = off;

    const int tier = (ws_size >= off_t1) ? 1 : (ws_size >= off_t2 ? 2 : 3);
    if (ws_size < off_base + (size_t)256 * 1024 * 2 + 256) return;  // cannot run

    hipMemsetAsync(hxbf, 0, (size_t)256 * 1024 * 2, stream);
    hipMemsetAsync(out + OUT_CX_OFF, 0, (size_t)256 * 1024 * 4, stream);

    // one-time weight convert+transpose
    for (int g = 0; g < 4; ++g)
        k_transpose<<<dim3(32, 64), 256, 0, stream>>>(
            Wg + (size_t)g * 2048 * 1024, wgT + (size_t)g * 1024 * 2048, 2048, 1024);
    const float* wsrc[3] = {Wq, Wk, Wv};
    for (int g = 0; g < 3; ++g)
        for (int wi = 0; wi < 3; ++wi)
            k_transpose<<<dim3(32, 32), 256, 0, stream>>>(
                wsrc[wi] + (size_t)g * 1024 * 1024,
                wqkvT + (size_t)g * 3072 * 1024 + (size_t)wi * 1024 * 1024, 1024, 1024);
    for (int g = 0; g < 3; ++g)
        k_transpose<<<dim3(32, 32), 256, 0, stream>>>(
            Wo + (size_t)g * 1024 * 1024, woT + (size_t)g * 1024 * 1024, 1024, 1024);

    if (tier <= 2) k_x2bf<<<2048, 256, 0, stream>>>(inputs, xbf, 16777216);
    if (tier == 1) k_xpre<<<dim3(32, 512), 256, 0, stream>>>(xbf, wgT, bg, xpre);

    for (int t = 0; t < 256; ++t) {
        if (tier == 3)
            k_x2bf<<<64, 256, 0, stream>>>(inputs + (size_t)t * 262144, xbf, 65536);
        if (tier == 1)
            k_hpre<1><<<dim3(64, 4), 256, 0, stream>>>(
                hxbf, xpre + (size_t)t * 256 * 4096, wgT, bg, prebf, gupd);
        else
            k_hpre<0><<<dim3(64, 4), 256, 0, stream>>>(
                hxbf, xbf + (tier == 2 ? (size_t)t * 262144 : 0), wgT, bg, prebf, gupd);
        k_qkv<<<dim3(48, 4, 3), 256, 0, stream>>>(prebf, wqkvT, bq, bk, bv, qkvbf);
        k_attn<<<dim3(256), 256, 0, stream>>>(qkvbf, aobf);
        k_gate<<<dim3(32, 8), 256, 0, stream>>>(aobf, woT, bo, gupd, hxbf, out, t);
    }
}